// Round 5
// baseline (398.039 us; speedup 1.0000x reference)
//
#include <hip/hip_runtime.h>
#include <hip/hip_bf16.h>

#define BB 64
#define SS 4096
#define HH 256
#define AA 128
#define MT 128      // M tile per block
#define BK 64       // K chunk
#define XST 72      // LDS row stride in f16 (64 + 8 pad -> 144 B, 16B aligned)

typedef __fp16 fp16v2 __attribute__((ext_vector_type(2)));   // cvt_pkrtz result type
typedef _Float16 half4v __attribute__((ext_vector_type(4)));
typedef _Float16 half8v __attribute__((ext_vector_type(8)));
typedef float floatx16 __attribute__((ext_vector_type(16)));

__device__ __forceinline__ float fast_tanh(float x) {
    float xc = fminf(fmaxf(x, -9.0f), 9.0f);
    float e = __expf(2.0f * xc);
    return 1.0f - __fdividef(2.0f, e + 1.0f);
}

// ---------------------------------------------------------------------------
// K0: W1 [H=256][A=128] fp32  ->  Wt [A=128][H=256] f16 (transposed) in d_ws
// ---------------------------------------------------------------------------
__global__ void convert_w1(const float* __restrict__ W1, _Float16* __restrict__ Wt) {
    int n = blockIdx.x;    // 0..127 (A)
    int k = threadIdx.x;   // 0..255 (H)
    Wt[n * HH + k] = (_Float16)W1[k * AA + n];
}

// ---------------------------------------------------------------------------
// K1: scores[m] = tanh(X[m,:]@W1 + b1) @ W2 + b2  via f16 MFMA (fp32 accum)
// Register-prefetch pipeline: issue chunk k+1 global loads BEFORE the MFMA
// phase of chunk k so HBM latency hides under compute; cvt via v_cvt_pkrtz.
// ---------------------------------------------------------------------------
__global__ __launch_bounds__(256) void score_mfma(
    const float* __restrict__ X,        // [B*S, H]
    const _Float16* __restrict__ Wt,    // [A, H] f16 (W1 transposed)
    const float* __restrict__ b1,       // [A]
    const float* __restrict__ W2,       // [A]
    const float* __restrict__ b2,       // [1]
    float* __restrict__ scores)         // [B*S]
{
    __shared__ float smem_f[9216];                       // 36864 B
    _Float16* Xs = (_Float16*)smem_f;                    // [128][XST]
    _Float16* Ws = (_Float16*)smem_f + MT * XST;         // [128][XST]
    float* part = smem_f;                                // [128][65] epilogue reuse

    const int tid   = threadIdx.x;
    const int m0    = blockIdx.x * MT;
    const int wid   = tid >> 6;
    const int lane  = tid & 63;
    const int lrow  = lane & 31;
    const int lhalf = lane >> 5;
    const int wr    = (wid & 1) * 64;
    const int wc    = (wid >> 1) * 64;

    floatx16 acc[2][2];
    #pragma unroll
    for (int i = 0; i < 2; ++i)
        #pragma unroll
        for (int j = 0; j < 2; ++j)
            #pragma unroll
            for (int r = 0; r < 16; ++r) acc[i][j][r] = 0.0f;

    float4 xv[8];
    uint4  wvv[4];

#define LOAD_CHUNK(K0)                                                         \
    do {                                                                       \
        _Pragma("unroll")                                                      \
        for (int p = 0; p < 8; ++p) {                                          \
            int idx = tid + p * 256;                                           \
            int row = idx >> 4, c4 = idx & 15;                                 \
            xv[p] = *(const float4*)(X + (size_t)(m0 + row) * HH + (K0) + c4 * 4); \
        }                                                                      \
        _Pragma("unroll")                                                      \
        for (int p = 0; p < 4; ++p) {                                          \
            int idx = tid + p * 256;                                           \
            int n = idx >> 3, u = idx & 7;                                     \
            wvv[p] = *(const uint4*)(Wt + (size_t)n * HH + (K0) + u * 8);      \
        }                                                                      \
    } while (0)

#define STORE_CHUNK()                                                          \
    do {                                                                       \
        _Pragma("unroll")                                                      \
        for (int p = 0; p < 8; ++p) {                                          \
            int idx = tid + p * 256;                                           \
            int row = idx >> 4, c4 = idx & 15;                                 \
            union { fp16v2 h2[2]; half4v h4; } u;                              \
            u.h2[0] = __builtin_amdgcn_cvt_pkrtz(xv[p].x, xv[p].y);            \
            u.h2[1] = __builtin_amdgcn_cvt_pkrtz(xv[p].z, xv[p].w);            \
            *(half4v*)(Xs + row * XST + c4 * 4) = u.h4;                        \
        }                                                                      \
        _Pragma("unroll")                                                      \
        for (int p = 0; p < 4; ++p) {                                          \
            int idx = tid + p * 256;                                           \
            int n = idx >> 3, u2 = idx & 7;                                    \
            *(uint4*)(Ws + n * XST + u2 * 8) = wvv[p];                         \
        }                                                                      \
    } while (0)

    LOAD_CHUNK(0);
    STORE_CHUNK();
    __syncthreads();

    #pragma unroll
    for (int c = 0; c < HH / BK; ++c) {
        if (c + 1 < HH / BK) LOAD_CHUNK((c + 1) * BK);   // prefetch, in flight during MFMA
        #pragma unroll
        for (int kk = 0; kk < BK; kk += 16) {
            half8v a0 = *(half8v*)(Xs + (wr + lrow) * XST + kk + lhalf * 8);
            half8v a1 = *(half8v*)(Xs + (wr + 32 + lrow) * XST + kk + lhalf * 8);
            half8v b0 = *(half8v*)(Ws + (wc + lrow) * XST + kk + lhalf * 8);
            half8v bq = *(half8v*)(Ws + (wc + 32 + lrow) * XST + kk + lhalf * 8);
            acc[0][0] = __builtin_amdgcn_mfma_f32_32x32x16_f16(a0, b0, acc[0][0], 0, 0, 0);
            acc[0][1] = __builtin_amdgcn_mfma_f32_32x32x16_f16(a0, bq, acc[0][1], 0, 0, 0);
            acc[1][0] = __builtin_amdgcn_mfma_f32_32x32x16_f16(a1, b0, acc[1][0], 0, 0, 0);
            acc[1][1] = __builtin_amdgcn_mfma_f32_32x32x16_f16(a1, bq, acc[1][1], 0, 0, 0);
        }
        __syncthreads();                                  // all waves done reading LDS
        if (c + 1 < HH / BK) {
            STORE_CHUNK();                                // write prefetched chunk
            __syncthreads();
        }
    }
#undef LOAD_CHUNK
#undef STORE_CHUNK

    // --- epilogue: tanh + dot(W2), per-row partials to LDS, then reduce ---
    const int cA = wc + lrow;
    const int cB = wc + 32 + lrow;
    const float b1A = b1[cA], b1B = b1[cB];
    const float w2A = W2[cA], w2B = W2[cB];
    #pragma unroll
    for (int i = 0; i < 2; ++i) {
        #pragma unroll
        for (int r = 0; r < 16; ++r) {
            float hA = fast_tanh(acc[i][0][r] + b1A) * w2A;
            float hB = fast_tanh(acc[i][1][r] + b1B) * w2B;
            int row = wr + i * 32 + (r & 3) + 8 * (r >> 2) + 4 * lhalf;
            part[row * 65 + (wid >> 1) * 32 + lrow] = hA + hB;
        }
    }
    __syncthreads();
    if (tid < MT) {
        float s = b2[0];
        #pragma unroll
        for (int c = 0; c < 64; ++c) s += part[tid * 65 + c];
        scores[m0 + tid] = s;
    }
}

// ---------------------------------------------------------------------------
// K2: entmax-1.5 over S per batch row. 10 bisection iters to bracket tau,
// then 4 Newton steps (f convex decreasing -> monotone from the left,
// quadratic convergence; strictly tighter than 35 bisections).
// In-place scores -> weights; zero-inits ctx.
// ---------------------------------------------------------------------------
__global__ __launch_bounds__(256) void entmax_kernel(
    float* __restrict__ buf, float* __restrict__ ctx)
{
    __shared__ float sred[8];
    const int b = blockIdx.x, tid = threadIdx.x;
    const int wid = tid >> 6;
    float* p = buf + (size_t)b * SS;

    float z[16];
    #pragma unroll
    for (int j = 0; j < 16; ++j) z[j] = p[tid + j * 256] * 0.5f;

    float m = -1e30f;
    #pragma unroll
    for (int j = 0; j < 16; ++j) m = fmaxf(m, z[j]);
    #pragma unroll
    for (int o = 1; o < 64; o <<= 1) m = fmaxf(m, __shfl_xor(m, o));
    if ((tid & 63) == 0) sred[wid] = m;
    __syncthreads();
    m = fmaxf(fmaxf(sred[0], sred[1]), fmaxf(sred[2], sred[3]));
    __syncthreads();
    #pragma unroll
    for (int j = 0; j < 16; ++j) z[j] -= m;

    float lo = -1.0f, hi = 0.0f;
    #pragma unroll 1
    for (int it = 0; it < 10; ++it) {
        float tau = 0.5f * (lo + hi);
        float s0 = 0.f, s1 = 0.f, s2 = 0.f, s3 = 0.f;
        #pragma unroll
        for (int j = 0; j < 16; j += 4) {
            float d0 = fmaxf(z[j]     - tau, 0.0f);
            float d1 = fmaxf(z[j + 1] - tau, 0.0f);
            float d2 = fmaxf(z[j + 2] - tau, 0.0f);
            float d3 = fmaxf(z[j + 3] - tau, 0.0f);
            s0 = fmaf(d0, d0, s0); s1 = fmaf(d1, d1, s1);
            s2 = fmaf(d2, d2, s2); s3 = fmaf(d3, d3, s3);
        }
        float s = (s0 + s1) + (s2 + s3);
        #pragma unroll
        for (int o = 1; o < 64; o <<= 1) s += __shfl_xor(s, o);
        if ((tid & 63) == 0) sred[wid] = s;
        __syncthreads();
        s = (sred[0] + sred[1]) + (sred[2] + sred[3]);
        __syncthreads();
        if (s >= 1.0f) lo = tau; else hi = tau;
    }

    float tau = lo;   // f(lo) >= 1 invariant -> Newton from the left
    #pragma unroll 1
    for (int it = 0; it < 4; ++it) {
        float s0 = 0.f, s1 = 0.f, t0 = 0.f, t1 = 0.f;
        #pragma unroll
        for (int j = 0; j < 16; j += 2) {
            float d0 = fmaxf(z[j]     - tau, 0.0f);
            float d1 = fmaxf(z[j + 1] - tau, 0.0f);
            s0 = fmaf(d0, d0, s0); s1 = fmaf(d1, d1, s1);
            t0 += d0; t1 += d1;
        }
        float s = s0 + s1, t = t0 + t1;
        #pragma unroll
        for (int o = 1; o < 64; o <<= 1) {
            s += __shfl_xor(s, o);
            t += __shfl_xor(t, o);
        }
        if ((tid & 63) == 0) { sred[wid * 2] = s; sred[wid * 2 + 1] = t; }
        __syncthreads();
        s = (sred[0] + sred[2]) + (sred[4] + sred[6]);
        t = (sred[1] + sred[3]) + (sred[5] + sred[7]);
        __syncthreads();
        tau = fminf(tau + (s - 1.0f) / (2.0f * t + 1e-30f), hi);
    }

    #pragma unroll
    for (int j = 0; j < 16; ++j) {
        float d = fmaxf(z[j] - tau, 0.0f);
        p[tid + j * 256] = d * d;
    }
    ctx[b * HH + tid] = 0.0f;
}

// ---------------------------------------------------------------------------
// K3: context[b,h] += sum_s X[b,s,h] * w[b,s]; entmax sparsity -> skip zeros
// ---------------------------------------------------------------------------
__global__ __launch_bounds__(256) void context_kernel(
    const float* __restrict__ X, const float* __restrict__ w,
    float* __restrict__ ctx)
{
    const int b  = blockIdx.y;
    const int s0 = blockIdx.x * 128;
    const int h  = threadIdx.x;

    __shared__ float ws_[128];
    __shared__ int nzflag;
    if (h == 0) nzflag = 0;
    __syncthreads();
    if (h < 128) {
        float v = w[(size_t)b * SS + s0 + h];
        ws_[h] = v;
        if (v > 0.0f) nzflag = 1;
    }
    __syncthreads();
    if (!nzflag) return;

    float acc = 0.0f;
    const float* xp = X + ((size_t)b * SS + s0) * HH + h;
    #pragma unroll 4
    for (int i = 0; i < 128; ++i) {
        float wv = ws_[i];
        if (wv != 0.0f) acc = fmaf(xp[(size_t)i * HH], wv, acc);
    }
    atomicAdd(&ctx[b * HH + h], acc);
}

extern "C" void kernel_launch(void* const* d_in, const int* in_sizes, int n_in,
                              void* d_out, int out_size, void* d_ws, size_t ws_size,
                              hipStream_t stream) {
    const float* X  = (const float*)d_in[0];
    const float* W1 = (const float*)d_in[1];
    const float* b1 = (const float*)d_in[2];
    const float* W2 = (const float*)d_in[3];
    const float* b2 = (const float*)d_in[4];

    float* out = (float*)d_out;
    float* ctx = out;            // [64*256]
    float* wts = out + BB * HH;  // [64*4096] scores -> weights
    _Float16* Wt = (_Float16*)d_ws;  // [128][256] f16, 64 KB

    convert_w1<<<AA, HH, 0, stream>>>(W1, Wt);
    score_mfma<<<(BB * SS) / MT, 256, 0, stream>>>(X, Wt, b1, W2, b2, wts);
    entmax_kernel<<<BB, 256, 0, stream>>>(wts, ctx);
    context_kernel<<<dim3(SS / 128, BB), 256, 0, stream>>>(X, wts, ctx);
}

// Round 6
// 395.012 us; speedup vs baseline: 1.0077x; 1.0077x over previous
//
#include <hip/hip_runtime.h>
#include <hip/hip_bf16.h>

#define BB 64
#define SS 4096
#define HH 256
#define AA 128
#define MT 128      // M tile per block
#define BK 64       // K chunk
#define XST 72      // LDS row stride in f16 (64 + 8 pad -> 144 B, 16B aligned)

typedef __fp16 fp16v2 __attribute__((ext_vector_type(2)));   // cvt_pkrtz result type
typedef _Float16 half4v __attribute__((ext_vector_type(4)));
typedef _Float16 half8v __attribute__((ext_vector_type(8)));
typedef float floatx16 __attribute__((ext_vector_type(16)));

__device__ __forceinline__ float fast_tanh(float x) {
    float xc = fminf(fmaxf(x, -9.0f), 9.0f);
    float e = __expf(2.0f * xc);
    return 1.0f - __fdividef(2.0f, e + 1.0f);
}

// ---------------------------------------------------------------------------
// K0: W1 [H=256][A=128] fp32  ->  Wt [A=128][H=256] f16 (transposed) in d_ws
// ---------------------------------------------------------------------------
__global__ void convert_w1(const float* __restrict__ W1, _Float16* __restrict__ Wt) {
    int n = blockIdx.x;    // 0..127 (A)
    int k = threadIdx.x;   // 0..255 (H)
    Wt[n * HH + k] = (_Float16)W1[k * AA + n];
}

// ---------------------------------------------------------------------------
// K1: scores[m] = tanh(X[m,:]@W1 + b1) @ W2 + b2  via f16 MFMA (fp32 accum)
// (unchanged this round — needs per-kernel timing before restructuring)
// ---------------------------------------------------------------------------
__global__ __launch_bounds__(256) void score_mfma(
    const float* __restrict__ X,        // [B*S, H]
    const _Float16* __restrict__ Wt,    // [A, H] f16 (W1 transposed)
    const float* __restrict__ b1,       // [A]
    const float* __restrict__ W2,       // [A]
    const float* __restrict__ b2,       // [1]
    float* __restrict__ scores)         // [B*S]
{
    __shared__ float smem_f[9216];                       // 36864 B
    _Float16* Xs = (_Float16*)smem_f;                    // [128][XST]
    _Float16* Ws = (_Float16*)smem_f + MT * XST;         // [128][XST]
    float* part = smem_f;                                // [128][65] epilogue reuse

    const int tid   = threadIdx.x;
    const int m0    = blockIdx.x * MT;
    const int wid   = tid >> 6;
    const int lane  = tid & 63;
    const int lrow  = lane & 31;
    const int lhalf = lane >> 5;
    const int wr    = (wid & 1) * 64;
    const int wc    = (wid >> 1) * 64;

    floatx16 acc[2][2];
    #pragma unroll
    for (int i = 0; i < 2; ++i)
        #pragma unroll
        for (int j = 0; j < 2; ++j)
            #pragma unroll
            for (int r = 0; r < 16; ++r) acc[i][j][r] = 0.0f;

    float4 xv[8];
    uint4  wvv[4];

#define LOAD_CHUNK(K0)                                                         \
    do {                                                                       \
        _Pragma("unroll")                                                      \
        for (int p = 0; p < 8; ++p) {                                          \
            int idx = tid + p * 256;                                           \
            int row = idx >> 4, c4 = idx & 15;                                 \
            xv[p] = *(const float4*)(X + (size_t)(m0 + row) * HH + (K0) + c4 * 4); \
        }                                                                      \
        _Pragma("unroll")                                                      \
        for (int p = 0; p < 4; ++p) {                                          \
            int idx = tid + p * 256;                                           \
            int n = idx >> 3, u = idx & 7;                                     \
            wvv[p] = *(const uint4*)(Wt + (size_t)n * HH + (K0) + u * 8);      \
        }                                                                      \
    } while (0)

#define STORE_CHUNK()                                                          \
    do {                                                                       \
        _Pragma("unroll")                                                      \
        for (int p = 0; p < 8; ++p) {                                          \
            int idx = tid + p * 256;                                           \
            int row = idx >> 4, c4 = idx & 15;                                 \
            union { fp16v2 h2[2]; half4v h4; } u;                              \
            u.h2[0] = __builtin_amdgcn_cvt_pkrtz(xv[p].x, xv[p].y);            \
            u.h2[1] = __builtin_amdgcn_cvt_pkrtz(xv[p].z, xv[p].w);            \
            *(half4v*)(Xs + row * XST + c4 * 4) = u.h4;                        \
        }                                                                      \
        _Pragma("unroll")                                                      \
        for (int p = 0; p < 4; ++p) {                                          \
            int idx = tid + p * 256;                                           \
            int n = idx >> 3, u2 = idx & 7;                                    \
            *(uint4*)(Ws + n * XST + u2 * 8) = wvv[p];                         \
        }                                                                      \
    } while (0)

    LOAD_CHUNK(0);
    STORE_CHUNK();
    __syncthreads();

    #pragma unroll
    for (int c = 0; c < HH / BK; ++c) {
        if (c + 1 < HH / BK) LOAD_CHUNK((c + 1) * BK);   // prefetch, in flight during MFMA
        #pragma unroll
        for (int kk = 0; kk < BK; kk += 16) {
            half8v a0 = *(half8v*)(Xs + (wr + lrow) * XST + kk + lhalf * 8);
            half8v a1 = *(half8v*)(Xs + (wr + 32 + lrow) * XST + kk + lhalf * 8);
            half8v b0 = *(half8v*)(Ws + (wc + lrow) * XST + kk + lhalf * 8);
            half8v bq = *(half8v*)(Ws + (wc + 32 + lrow) * XST + kk + lhalf * 8);
            acc[0][0] = __builtin_amdgcn_mfma_f32_32x32x16_f16(a0, b0, acc[0][0], 0, 0, 0);
            acc[0][1] = __builtin_amdgcn_mfma_f32_32x32x16_f16(a0, bq, acc[0][1], 0, 0, 0);
            acc[1][0] = __builtin_amdgcn_mfma_f32_32x32x16_f16(a1, b0, acc[1][0], 0, 0, 0);
            acc[1][1] = __builtin_amdgcn_mfma_f32_32x32x16_f16(a1, bq, acc[1][1], 0, 0, 0);
        }
        __syncthreads();                                  // all waves done reading LDS
        if (c + 1 < HH / BK) {
            STORE_CHUNK();                                // write prefetched chunk
            __syncthreads();
        }
    }
#undef LOAD_CHUNK
#undef STORE_CHUNK

    // --- epilogue: tanh + dot(W2), per-row partials to LDS, then reduce ---
    const int cA = wc + lrow;
    const int cB = wc + 32 + lrow;
    const float b1A = b1[cA], b1B = b1[cB];
    const float w2A = W2[cA], w2B = W2[cB];
    #pragma unroll
    for (int i = 0; i < 2; ++i) {
        #pragma unroll
        for (int r = 0; r < 16; ++r) {
            float hA = fast_tanh(acc[i][0][r] + b1A) * w2A;
            float hB = fast_tanh(acc[i][1][r] + b1B) * w2B;
            int row = wr + i * 32 + (r & 3) + 8 * (r >> 2) + 4 * lhalf;
            part[row * 65 + (wid >> 1) * 32 + lrow] = hA + hB;
        }
    }
    __syncthreads();
    if (tid < MT) {
        float s = b2[0];
        #pragma unroll
        for (int c = 0; c < 64; ++c) s += part[tid * 65 + c];
        scores[m0 + tid] = s;
    }
}

// ---------------------------------------------------------------------------
// K2 (fused): entmax-1.5 over S per batch row (10 bisect + 4 Newton), then
// support compaction into LDS and the context reduction in the same block.
// Each thread owns 16 CONTIGUOUS s values (float4-vectorized I/O). Context:
// block-uniform loop over compacted (s, w) pairs, thread h = tid reads
// X[b, s, h] (coalesced 1 KB per row), no atomics, direct ctx store.
// ---------------------------------------------------------------------------
__global__ __launch_bounds__(256) void entmax_ctx_kernel(
    const float* __restrict__ X, float* __restrict__ buf, float* __restrict__ ctx)
{
    __shared__ float sred[8];
    __shared__ int   cnt;
    __shared__ int   sidx[SS];    // 16 KB (worst-case full support)
    __shared__ float swt[SS];     // 16 KB

    const int b = blockIdx.x, tid = threadIdx.x;
    const int wid = tid >> 6;
    float* p = buf + (size_t)b * SS;
    const float4* p4 = (const float4*)p;

    if (tid == 0) cnt = 0;

    float z[16];
    #pragma unroll
    for (int jj = 0; jj < 4; ++jj) {
        float4 v = p4[tid * 4 + jj];
        z[jj * 4 + 0] = v.x * 0.5f; z[jj * 4 + 1] = v.y * 0.5f;
        z[jj * 4 + 2] = v.z * 0.5f; z[jj * 4 + 3] = v.w * 0.5f;
    }

    float m = -1e30f;
    #pragma unroll
    for (int j = 0; j < 16; ++j) m = fmaxf(m, z[j]);
    #pragma unroll
    for (int o = 1; o < 64; o <<= 1) m = fmaxf(m, __shfl_xor(m, o));
    if ((tid & 63) == 0) sred[wid] = m;
    __syncthreads();
    m = fmaxf(fmaxf(sred[0], sred[1]), fmaxf(sred[2], sred[3]));
    __syncthreads();
    #pragma unroll
    for (int j = 0; j < 16; ++j) z[j] -= m;

    float lo = -1.0f, hi = 0.0f;
    #pragma unroll 1
    for (int it = 0; it < 10; ++it) {
        float tau = 0.5f * (lo + hi);
        float s0 = 0.f, s1 = 0.f, s2 = 0.f, s3 = 0.f;
        #pragma unroll
        for (int j = 0; j < 16; j += 4) {
            float d0 = fmaxf(z[j]     - tau, 0.0f);
            float d1 = fmaxf(z[j + 1] - tau, 0.0f);
            float d2 = fmaxf(z[j + 2] - tau, 0.0f);
            float d3 = fmaxf(z[j + 3] - tau, 0.0f);
            s0 = fmaf(d0, d0, s0); s1 = fmaf(d1, d1, s1);
            s2 = fmaf(d2, d2, s2); s3 = fmaf(d3, d3, s3);
        }
        float s = (s0 + s1) + (s2 + s3);
        #pragma unroll
        for (int o = 1; o < 64; o <<= 1) s += __shfl_xor(s, o);
        if ((tid & 63) == 0) sred[wid] = s;
        __syncthreads();
        s = (sred[0] + sred[1]) + (sred[2] + sred[3]);
        __syncthreads();
        if (s >= 1.0f) lo = tau; else hi = tau;
    }

    float tau = lo;   // f(lo) >= 1 invariant -> Newton from the left
    #pragma unroll 1
    for (int it = 0; it < 4; ++it) {
        float s0 = 0.f, s1 = 0.f, t0 = 0.f, t1 = 0.f;
        #pragma unroll
        for (int j = 0; j < 16; j += 2) {
            float d0 = fmaxf(z[j]     - tau, 0.0f);
            float d1 = fmaxf(z[j + 1] - tau, 0.0f);
            s0 = fmaf(d0, d0, s0); s1 = fmaf(d1, d1, s1);
            t0 += d0; t1 += d1;
        }
        float s = s0 + s1, t = t0 + t1;
        #pragma unroll
        for (int o = 1; o < 64; o <<= 1) {
            s += __shfl_xor(s, o);
            t += __shfl_xor(t, o);
        }
        if ((tid & 63) == 0) { sred[wid * 2] = s; sred[wid * 2 + 1] = t; }
        __syncthreads();
        s = (sred[0] + sred[2]) + (sred[4] + sred[6]);
        t = (sred[1] + sred[3]) + (sred[5] + sred[7]);
        __syncthreads();
        tau = fminf(tau + (s - 1.0f) / (2.0f * t + 1e-30f), hi);
    }

    // --- weights out (vectorized) + support compaction into LDS ---
    float4* p4w = (float4*)p;
    #pragma unroll
    for (int jj = 0; jj < 4; ++jj) {
        float w[4];
        #pragma unroll
        for (int k = 0; k < 4; ++k) {
            float d = fmaxf(z[jj * 4 + k] - tau, 0.0f);
            w[k] = d * d;
            if (w[k] > 0.0f) {
                int pos = atomicAdd(&cnt, 1);
                sidx[pos] = tid * 16 + jj * 4 + k;
                swt[pos]  = w[k];
            }
        }
        p4w[tid * 4 + jj] = make_float4(w[0], w[1], w[2], w[3]);
    }
    __syncthreads();

    // --- context: ctx[b, tid] = sum over support of w * X[b, s, tid] ---
    const int n = cnt;
    const float* xb = X + (size_t)b * SS * HH + tid;
    float a0 = 0.f, a1 = 0.f, a2 = 0.f, a3 = 0.f;
    int i = 0;
    for (; i + 4 <= n; i += 4) {
        a0 = fmaf(swt[i    ], xb[(size_t)sidx[i    ] * HH], a0);
        a1 = fmaf(swt[i + 1], xb[(size_t)sidx[i + 1] * HH], a1);
        a2 = fmaf(swt[i + 2], xb[(size_t)sidx[i + 2] * HH], a2);
        a3 = fmaf(swt[i + 3], xb[(size_t)sidx[i + 3] * HH], a3);
    }
    for (; i < n; ++i) a0 = fmaf(swt[i], xb[(size_t)sidx[i] * HH], a0);
    ctx[b * HH + tid] = (a0 + a1) + (a2 + a3);
}

extern "C" void kernel_launch(void* const* d_in, const int* in_sizes, int n_in,
                              void* d_out, int out_size, void* d_ws, size_t ws_size,
                              hipStream_t stream) {
    const float* X  = (const float*)d_in[0];
    const float* W1 = (const float*)d_in[1];
    const float* b1 = (const float*)d_in[2];
    const float* W2 = (const float*)d_in[3];
    const float* b2 = (const float*)d_in[4];

    float* out = (float*)d_out;
    float* ctx = out;            // [64*256]
    float* wts = out + BB * HH;  // [64*4096] scores -> weights
    _Float16* Wt = (_Float16*)d_ws;  // [128][256] f16, 64 KB

    convert_w1<<<AA, HH, 0, stream>>>(W1, Wt);
    score_mfma<<<(BB * SS) / MT, 256, 0, stream>>>(X, Wt, b1, W2, b2, wts);
    entmax_ctx_kernel<<<BB, 256, 0, stream>>>(X, wts, ctx);
}

// Round 8
// 391.177 us; speedup vs baseline: 1.0175x; 1.0098x over previous
//
#include <hip/hip_runtime.h>
#include <hip/hip_bf16.h>

#define BB 64
#define SS 4096
#define HH 256
#define AA 128
#define MT 128      // M tile per block
#define BK 64       // K chunk
#define XST 72      // LDS row stride in f16 (64 + 8 pad -> 144 B, 16B aligned)

typedef __fp16 fp16v2 __attribute__((ext_vector_type(2)));   // cvt_pkrtz result type
typedef _Float16 half4v __attribute__((ext_vector_type(4)));
typedef _Float16 half8v __attribute__((ext_vector_type(8)));
typedef float floatx16 __attribute__((ext_vector_type(16)));

__device__ __forceinline__ float fast_tanh(float x) {
    float xc = fminf(fmaxf(x, -9.0f), 9.0f);
    float e = __expf(2.0f * xc);
    return 1.0f - __fdividef(2.0f, e + 1.0f);
}

// ---------------------------------------------------------------------------
// K0: W1 [H=256][A=128] fp32  ->  Wt [A=128][H=256] f16 (transposed) in d_ws
// ---------------------------------------------------------------------------
__global__ void convert_w1(const float* __restrict__ W1, _Float16* __restrict__ Wt) {
    int n = blockIdx.x;    // 0..127 (A)
    int k = threadIdx.x;   // 0..255 (H)
    Wt[n * HH + k] = (_Float16)W1[k * AA + n];
}

// ---------------------------------------------------------------------------
// K1: scores[m] = tanh(X[m,:]@W1 + b1) @ W2 + b2  via f16 MFMA (fp32 accum)
// R7: REVERT register-prefetch (T2 experiment). Staging goes straight
// global->cvt->LDS with no long-lived registers across the MFMA phase;
// occupancy (not intra-wave pipelining) is the latency-hiding mechanism.
// ---------------------------------------------------------------------------
__global__ __launch_bounds__(256) void score_mfma(
    const float* __restrict__ X,        // [B*S, H]
    const _Float16* __restrict__ Wt,    // [A, H] f16 (W1 transposed)
    const float* __restrict__ b1,       // [A]
    const float* __restrict__ W2,       // [A]
    const float* __restrict__ b2,       // [1]
    float* __restrict__ scores)         // [B*S]
{
    __shared__ float smem_f[9216];                       // 36864 B
    _Float16* Xs = (_Float16*)smem_f;                    // [128][XST]
    _Float16* Ws = (_Float16*)smem_f + MT * XST;         // [128][XST]
    float* part = smem_f;                                // [128][65] epilogue reuse

    const int tid   = threadIdx.x;
    const int m0    = blockIdx.x * MT;
    const int wid   = tid >> 6;
    const int lane  = tid & 63;
    const int lrow  = lane & 31;
    const int lhalf = lane >> 5;
    const int wr    = (wid & 1) * 64;
    const int wc    = (wid >> 1) * 64;

    floatx16 acc[2][2];
    #pragma unroll
    for (int i = 0; i < 2; ++i)
        #pragma unroll
        for (int j = 0; j < 2; ++j)
            #pragma unroll
            for (int r = 0; r < 16; ++r) acc[i][j][r] = 0.0f;

    for (int k0 = 0; k0 < HH; k0 += BK) {
        // --- stage X chunk: 128 rows x 64 k fp32 -> f16 LDS (pkrtz cvt) ---
        #pragma unroll
        for (int p = 0; p < 8; ++p) {
            int idx = tid + p * 256;
            int row = idx >> 4, c4 = idx & 15;
            float4 v = *(const float4*)(X + (size_t)(m0 + row) * HH + k0 + c4 * 4);
            union { fp16v2 h2[2]; half4v h4; } u;
            u.h2[0] = __builtin_amdgcn_cvt_pkrtz(v.x, v.y);
            u.h2[1] = __builtin_amdgcn_cvt_pkrtz(v.z, v.w);
            *(half4v*)(Xs + row * XST + c4 * 4) = u.h4;
        }
        // --- stage Wt chunk: 128 n-rows x 64 k f16, 16B vector loads ---
        #pragma unroll
        for (int p = 0; p < 4; ++p) {
            int idx = tid + p * 256;
            int n = idx >> 3, u2 = idx & 7;
            *(uint4*)(Ws + n * XST + u2 * 8) =
                *(const uint4*)(Wt + (size_t)n * HH + k0 + u2 * 8);
        }
        __syncthreads();
        // --- MFMA inner loop ---
        #pragma unroll
        for (int kk = 0; kk < BK; kk += 16) {
            half8v a0 = *(half8v*)(Xs + (wr + lrow) * XST + kk + lhalf * 8);
            half8v a1 = *(half8v*)(Xs + (wr + 32 + lrow) * XST + kk + lhalf * 8);
            half8v b0 = *(half8v*)(Ws + (wc + lrow) * XST + kk + lhalf * 8);
            half8v bq = *(half8v*)(Ws + (wc + 32 + lrow) * XST + kk + lhalf * 8);
            acc[0][0] = __builtin_amdgcn_mfma_f32_32x32x16_f16(a0, b0, acc[0][0], 0, 0, 0);
            acc[0][1] = __builtin_amdgcn_mfma_f32_32x32x16_f16(a0, bq, acc[0][1], 0, 0, 0);
            acc[1][0] = __builtin_amdgcn_mfma_f32_32x32x16_f16(a1, b0, acc[1][0], 0, 0, 0);
            acc[1][1] = __builtin_amdgcn_mfma_f32_32x32x16_f16(a1, bq, acc[1][1], 0, 0, 0);
        }
        __syncthreads();
    }

    // --- epilogue: tanh + dot(W2), per-row partials to LDS, then reduce ---
    const int cA = wc + lrow;
    const int cB = wc + 32 + lrow;
    const float b1A = b1[cA], b1B = b1[cB];
    const float w2A = W2[cA], w2B = W2[cB];
    #pragma unroll
    for (int i = 0; i < 2; ++i) {
        #pragma unroll
        for (int r = 0; r < 16; ++r) {
            float hA = fast_tanh(acc[i][0][r] + b1A) * w2A;
            float hB = fast_tanh(acc[i][1][r] + b1B) * w2B;
            int row = wr + i * 32 + (r & 3) + 8 * (r >> 2) + 4 * lhalf;
            part[row * 65 + (wid >> 1) * 32 + lrow] = hA + hB;
        }
    }
    __syncthreads();
    if (tid < MT) {
        float s = b2[0];
        #pragma unroll
        for (int c = 0; c < 64; ++c) s += part[tid * 65 + c];
        scores[m0 + tid] = s;
    }
}

// ---------------------------------------------------------------------------
// K2 (fused): entmax-1.5 over S per batch row (10 bisect + 4 Newton), then
// support compaction into LDS and the context reduction in the same block.
// ---------------------------------------------------------------------------
__global__ __launch_bounds__(256) void entmax_ctx_kernel(
    const float* __restrict__ X, float* __restrict__ buf, float* __restrict__ ctx)
{
    __shared__ float sred[8];
    __shared__ int   cnt;
    __shared__ int   sidx[SS];    // 16 KB (worst-case full support)
    __shared__ float swt[SS];     // 16 KB

    const int b = blockIdx.x, tid = threadIdx.x;
    const int wid = tid >> 6;
    float* p = buf + (size_t)b * SS;
    const float4* p4 = (const float4*)p;

    if (tid == 0) cnt = 0;

    float z[16];
    #pragma unroll
    for (int jj = 0; jj < 4; ++jj) {
        float4 v = p4[tid * 4 + jj];
        z[jj * 4 + 0] = v.x * 0.5f; z[jj * 4 + 1] = v.y * 0.5f;
        z[jj * 4 + 2] = v.z * 0.5f; z[jj * 4 + 3] = v.w * 0.5f;
    }

    float m = -1e30f;
    #pragma unroll
    for (int j = 0; j < 16; ++j) m = fmaxf(m, z[j]);
    #pragma unroll
    for (int o = 1; o < 64; o <<= 1) m = fmaxf(m, __shfl_xor(m, o));
    if ((tid & 63) == 0) sred[wid] = m;
    __syncthreads();
    m = fmaxf(fmaxf(sred[0], sred[1]), fmaxf(sred[2], sred[3]));
    __syncthreads();
    #pragma unroll
    for (int j = 0; j < 16; ++j) z[j] -= m;

    float lo = -1.0f, hi = 0.0f;
    #pragma unroll 1
    for (int it = 0; it < 10; ++it) {
        float tau = 0.5f * (lo + hi);
        float s0 = 0.f, s1 = 0.f, s2 = 0.f, s3 = 0.f;
        #pragma unroll
        for (int j = 0; j < 16; j += 4) {
            float d0 = fmaxf(z[j]     - tau, 0.0f);
            float d1 = fmaxf(z[j + 1] - tau, 0.0f);
            float d2 = fmaxf(z[j + 2] - tau, 0.0f);
            float d3 = fmaxf(z[j + 3] - tau, 0.0f);
            s0 = fmaf(d0, d0, s0); s1 = fmaf(d1, d1, s1);
            s2 = fmaf(d2, d2, s2); s3 = fmaf(d3, d3, s3);
        }
        float s = (s0 + s1) + (s2 + s3);
        #pragma unroll
        for (int o = 1; o < 64; o <<= 1) s += __shfl_xor(s, o);
        if ((tid & 63) == 0) sred[wid] = s;
        __syncthreads();
        s = (sred[0] + sred[1]) + (sred[2] + sred[3]);
        __syncthreads();
        if (s >= 1.0f) lo = tau; else hi = tau;
    }

    float tau = lo;   // f(lo) >= 1 invariant -> Newton from the left
    #pragma unroll 1
    for (int it = 0; it < 4; ++it) {
        float s0 = 0.f, s1 = 0.f, t0 = 0.f, t1 = 0.f;
        #pragma unroll
        for (int j = 0; j < 16; j += 2) {
            float d0 = fmaxf(z[j]     - tau, 0.0f);
            float d1 = fmaxf(z[j + 1] - tau, 0.0f);
            s0 = fmaf(d0, d0, s0); s1 = fmaf(d1, d1, s1);
            t0 += d0; t1 += d1;
        }
        float s = s0 + s1, t = t0 + t1;
        #pragma unroll
        for (int o = 1; o < 64; o <<= 1) {
            s += __shfl_xor(s, o);
            t += __shfl_xor(t, o);
        }
        if ((tid & 63) == 0) { sred[wid * 2] = s; sred[wid * 2 + 1] = t; }
        __syncthreads();
        s = (sred[0] + sred[2]) + (sred[4] + sred[6]);
        t = (sred[1] + sred[3]) + (sred[5] + sred[7]);
        __syncthreads();
        tau = fminf(tau + (s - 1.0f) / (2.0f * t + 1e-30f), hi);
    }

    // --- weights out (vectorized) + support compaction into LDS ---
    float4* p4w = (float4*)p;
    #pragma unroll
    for (int jj = 0; jj < 4; ++jj) {
        float w[4];
        #pragma unroll
        for (int k = 0; k < 4; ++k) {
            float d = fmaxf(z[jj * 4 + k] - tau, 0.0f);
            w[k] = d * d;
            if (w[k] > 0.0f) {
                int pos = atomicAdd(&cnt, 1);
                sidx[pos] = tid * 16 + jj * 4 + k;
                swt[pos]  = w[k];
            }
        }
        p4w[tid * 4 + jj] = make_float4(w[0], w[1], w[2], w[3]);
    }
    __syncthreads();

    // --- context: ctx[b, tid] = sum over support of w * X[b, s, tid] ---
    const int n = cnt;
    const float* xb = X + (size_t)b * SS * HH + tid;
    float a0 = 0.f, a1 = 0.f, a2 = 0.f, a3 = 0.f;
    int i = 0;
    for (; i + 4 <= n; i += 4) {
        a0 = fmaf(swt[i    ], xb[(size_t)sidx[i    ] * HH], a0);
        a1 = fmaf(swt[i + 1], xb[(size_t)sidx[i + 1] * HH], a1);
        a2 = fmaf(swt[i + 2], xb[(size_t)sidx[i + 2] * HH], a2);
        a3 = fmaf(swt[i + 3], xb[(size_t)sidx[i + 3] * HH], a3);
    }
    for (; i < n; ++i) a0 = fmaf(swt[i], xb[(size_t)sidx[i] * HH], a0);
    ctx[b * HH + tid] = (a0 + a1) + (a2 + a3);
}

extern "C" void kernel_launch(void* const* d_in, const int* in_sizes, int n_in,
                              void* d_out, int out_size, void* d_ws, size_t ws_size,
                              hipStream_t stream) {
    const float* X  = (const float*)d_in[0];
    const float* W1 = (const float*)d_in[1];
    const float* b1 = (const float*)d_in[2];
    const float* W2 = (const float*)d_in[3];
    const float* b2 = (const float*)d_in[4];

    float* out = (float*)d_out;
    float* ctx = out;            // [64*256]
    float* wts = out + BB * HH;  // [64*4096] scores -> weights
    _Float16* Wt = (_Float16*)d_ws;  // [128][256] f16, 64 KB

    convert_w1<<<AA, HH, 0, stream>>>(W1, Wt);
    score_mfma<<<(BB * SS) / MT, 256, 0, stream>>>(X, Wt, b1, W2, b2, wts);
    entmax_ctx_kernel<<<BB, 256, 0, stream>>>(X, wts, ctx);
}